// Round 1
// baseline (154.847 us; speedup 1.0000x reference)
//
#include <hip/hip_runtime.h>
#include <math.h>

#define BB 8
#define NN 1000
#define CC 81
#define NC 80                     // foreground classes
#define IMG_W_M1 1332.0f
#define IMG_H_M1 799.0f
#define SCORE_THRESH 0.05f
#define NMS_THRESH 0.5f
#define DETS 100
#define CAP 8192                  // per-image candidate capacity after NMS
#define DW_CLIP 4.135166556742356f  // log(1000/16) rounded to f32
#define NBINS 4096
#define SELCAP 1024

// ws layout (bytes):
//   [0, 64)                       u32[16]: counters[0..7] = survivor counts,
//                                          counters[8..15] = per-image done-block counts
//   [64, 64 + 80*8000*4)          probT: [80][8000] foreground probs, class-major (transposed)
//   [2560064, 2560064+8*CAP*6*4)  candidates: per image, CAP x {score, x1,y1,x2,y2, flatidx(int)}

// Kernel 1: per-row softmax, written TRANSPOSED so kernel 2 reads coalesced.
// 125 blocks x 64 threads (one wave each) spreads the latency-bound row loops
// over 125 CUs instead of 32. Math is bit-identical to the previous version:
// serial fmax over c=0..80, serial sum of expf in the same order, IEEE divide.
__global__ __launch_bounds__(64) void softmax_probs(
    const float* __restrict__ logits, float* __restrict__ probT,
    unsigned* __restrict__ counters) {
#pragma clang fp contract(off)
  if (blockIdx.x == 0 && threadIdx.x < 16) counters[threadIdx.x] = 0u;
  int r = blockIdx.x * 64 + threadIdx.x;
  if (r >= BB * NN) return;
  const float* l = logits + (size_t)r * CC;
  float m = l[0];
#pragma unroll
  for (int c = 1; c < CC; ++c) m = fmaxf(m, l[c]);
  float e[CC];
  float s = 0.0f;
#pragma unroll
  for (int c = 0; c < CC; ++c) { e[c] = expf(l[c] - m); s += e[c]; }
  // write foreground probs transposed: for fixed c, lanes write 64 consecutive
  // floats -> one coalesced 256B segment per store.
#pragma unroll
  for (int c = 1; c < CC; ++c)
    probT[(size_t)(c - 1) * (BB * NN) + r] = e[c] / s;
}

// Kernel 2: per-(image,class) NMS; the LAST block to finish per image runs the
// per-image top-K inline (saves the 3rd launch + its 8-block tail).
__global__ __launch_bounds__(256) void per_class_nms_topk(
    const float* __restrict__ probT, const float* __restrict__ reg,
    const float* __restrict__ props, unsigned* __restrict__ counters,
    float* __restrict__ cand, float* __restrict__ dets_out,
    float* __restrict__ labels_out) {
#pragma clang fp contract(off)
  // 33 KB overlay: NMS-phase arrays and topk-phase arrays never live at the
  // same time (topk runs only after the final barrier in the last block).
  __shared__ __align__(16) char smem[33024];
  float*         s_score  = (float*)(smem);          //  4000 B
  int*           s_idx    = (int*)(smem + 4000);     //  4000 B
  float*         s_sscore = (float*)(smem + 8000);   //  4000 B
  int*           s_sidx   = (int*)(smem + 12000);    //  4000 B
  float*         s_box    = (float*)(smem + 16000);  // 16000 B
  unsigned char* s_keep   = (unsigned char*)(smem + 32000);  // 1000 B
  __shared__ int s_cnt;
  __shared__ unsigned s_base;
  __shared__ int s_last;
  __shared__ int s_m, s_cut;

  const int img = blockIdx.x / NC;
  const int cls = blockIdx.x % NC + 1;   // foreground class id 1..80
  const int t = threadIdx.x;

  if (t == 0) s_cnt = 0;
  __syncthreads();

  // Phase 1: collect candidates with prob > thresh — coalesced column read,
  // no expf (precomputed in kernel 1, bitwise-identical values).
  const float* pcol = probT + (size_t)(cls - 1) * (BB * NN) + img * NN;
  for (int r = t; r < NN; r += 256) {
    float p = pcol[r];
    if (p > SCORE_THRESH) {
      int pos = atomicAdd(&s_cnt, 1);
      s_score[pos] = p;
      s_idx[pos] = r;
    }
  }
  __syncthreads();
  const int n = s_cnt;

  // Phase 2: rank sort by (score desc, original row asc) == stable argsort(-scores)
  for (int i = t; i < n; i += 256) {
    float si = s_score[i];
    int   ii = s_idx[i];
    int rank = 0;
#pragma unroll 8
    for (int j = 0; j < n; ++j) {
      float sj = s_score[j];
      rank += (int)((sj > si) | ((sj == si) & (s_idx[j] < ii)));
    }
    s_sscore[rank] = si;
    s_sidx[rank] = ii;
  }
  __syncthreads();

  // Phase 3: decode + clip boxes for sorted candidates (BoxCoder.decode, TO_REMOVE=1)
  for (int i = t; i < n; i += 256) {
    int r = s_sidx[i];
    int row = img * NN + r;
    float x1 = props[row * 4 + 0], y1 = props[row * 4 + 1];
    float x2 = props[row * 4 + 2], y2 = props[row * 4 + 3];
    float w = x2 - x1 + 1.0f, h = y2 - y1 + 1.0f;
    float cx = x1 + 0.5f * w,  cy = y1 + 0.5f * h;
    const float* rg = reg + (size_t)row * (CC * 4) + cls * 4;
    float dx = rg[0] / 10.0f, dy = rg[1] / 10.0f;
    float dw = fminf(rg[2] / 5.0f, DW_CLIP);
    float dh = fminf(rg[3] / 5.0f, DW_CLIP);
    float pcx = dx * w + cx, pcy = dy * h + cy;
    float pw = expf(dw) * w, ph = expf(dh) * h;
    float bx1 = pcx - 0.5f * pw;
    float by1 = pcy - 0.5f * ph;
    float bx2 = pcx + 0.5f * pw - 1.0f;
    float by2 = pcy + 0.5f * ph - 1.0f;
    bx1 = fminf(fmaxf(bx1, 0.0f), IMG_W_M1);
    bx2 = fminf(fmaxf(bx2, 0.0f), IMG_W_M1);
    by1 = fminf(fmaxf(by1, 0.0f), IMG_H_M1);
    by2 = fminf(fmaxf(by2, 0.0f), IMG_H_M1);
    s_box[i * 4 + 0] = bx1;
    s_box[i * 4 + 1] = by1;
    s_box[i * 4 + 2] = bx2;
    s_box[i * 4 + 3] = by2;
    s_keep[i] = 1;
  }
  __syncthreads();

  // Phase 4: greedy NMS (torchvision IoU, no +1), identical to reference semantics
  for (int i = 0; i < n; ++i) {
    if (s_keep[i]) {   // uniform branch: all threads read same LDS value
      float ax1 = s_box[i * 4 + 0], ay1 = s_box[i * 4 + 1];
      float ax2 = s_box[i * 4 + 2], ay2 = s_box[i * 4 + 3];
      float areaA = (ax2 - ax1) * (ay2 - ay1);
      for (int j = i + 1 + t; j < n; j += 256) {
        if (!s_keep[j]) continue;
        float bx1 = s_box[j * 4 + 0], by1 = s_box[j * 4 + 1];
        float bx2 = s_box[j * 4 + 2], by2 = s_box[j * 4 + 3];
        float areaB = (bx2 - bx1) * (by2 - by1);
        float wx = fmaxf(fminf(ax2, bx2) - fmaxf(ax1, bx1), 0.0f);
        float wy = fmaxf(fminf(ay2, by2) - fmaxf(ay1, by1), 0.0f);
        float inter = wx * wy;
        float iou = inter / ((areaA + areaB) - inter + 1e-9f);
        if (iou > NMS_THRESH) s_keep[j] = 0;
      }
    }
    __syncthreads();
  }

  // Phase 5: emit survivors — one global atomic per block, coalesced writes.
  if (t == 0) {
    int tot = 0;
    for (int j = 0; j < n; ++j) tot += s_keep[j];
    s_base = (tot > 0) ? atomicAdd(&counters[img], (unsigned)tot) : 0u;
  }
  __syncthreads();
  for (int i = t; i < n; i += 256) {
    if (s_keep[i]) {
      int pos = 0;
#pragma unroll 4
      for (int j = 0; j < i; ++j) pos += (int)s_keep[j];
      unsigned gpos = s_base + (unsigned)pos;
      if (gpos < CAP) {
        float* c = cand + ((size_t)img * CAP + gpos) * 6;
        c[0] = s_sscore[i];
        c[1] = s_box[i * 4 + 0];
        c[2] = s_box[i * 4 + 1];
        c[3] = s_box[i * 4 + 2];
        c[4] = s_box[i * 4 + 3];
        ((int*)c)[5] = (cls - 1) * NN + s_sidx[i];   // flat idx for tie-break + label
      }
    }
  }

  // Release our candidate writes at device scope, then signal completion.
  // Pattern: every thread fences, barrier, t0 bumps the done-counter. The block
  // observing done==NC-1 knows all 79 other blocks' fences happened-before.
  __threadfence();
  __syncthreads();
  if (t == 0) {
    unsigned d = atomicAdd(&counters[8 + img], 1u);
    s_last = (d == (unsigned)(NC - 1)) ? 1 : 0;
  }
  __syncthreads();
  if (!s_last) return;          // uniform: s_last is shared
  __threadfence();              // acquire side: invalidate L1/L2 before reading
                                // other blocks' candidates (cross-XCD safe)

  // ---- Fused per-image top-K (runs in exactly one block per image) ----
  unsigned* hist  = (unsigned*)(smem);          // 16384 B (overlays NMS arrays)
  float*    s_ssc = (float*)(smem + 16384);     //  4096 B
  int*      s_sfl = (int*)(smem + 20480);       //  4096 B
  int*      s_sci = (int*)(smem + 24576);       //  4096 B

  int n2 = (int)counters[img];
  if (n2 > CAP) n2 = CAP;
  const int K = (n2 < DETS) ? n2 : DETS;
  const float* cbase = cand + (size_t)img * CAP * 6;
  float* dbase = dets_out + (size_t)img * DETS * 5;

  if (t == 0) { s_m = 0; s_cut = 0; }
  // Defaults for slots beyond candidate count (ranks 0..K-1 all get written
  // exactly once below, since ranks are unique).
  for (int k = t; k < DETS; k += 256) {
    if (k >= K) {
      float* dst = dbase + (size_t)k * 5;
      dst[0] = 0.0f; dst[1] = 0.0f; dst[2] = 0.0f; dst[3] = 0.0f; dst[4] = 0.0f;
      labels_out[img * DETS + k] = -1.0f;
    }
  }
  for (int b = t; b < NBINS; b += 256) hist[b] = 0u;
  __syncthreads();

  // Histogram of scores. bin = floor(score*4096) is monotone in score, so
  // {bin >= cut} is upward-closed: contains the exact global top-K, and
  // within-set ranks equal global ranks.
  if (K > 0) {
    for (int i = t; i < n2; i += 256) {
      float sc = cbase[i * 6];
      int bin = (int)(sc * (float)NBINS);
      if (bin > NBINS - 1) bin = NBINS - 1;
      atomicAdd(&hist[bin], 1u);
    }
  }
  __syncthreads();

  // Wave 0: find largest cutoff bin T with count(bin >= T) >= K.
  if (t < 64 && K > 0) {
    unsigned s = 0;
#pragma unroll
    for (int b = 0; b < 64; ++b) s += hist[t * 64 + b];
    unsigned suf = s;                       // suffix-inclusive scan over 64 superbins
    for (int d = 1; d < 64; d <<= 1) {
      unsigned o = __shfl_down(suf, d);
      if (t + d < 64) suf += o;
    }
    unsigned long long m1 = __ballot(suf >= (unsigned)K);
    int S = 63 - __clzll(m1);               // largest superbin with suffix >= K
    unsigned tail = 0;
    if (S < 63) tail = __shfl(suf, S + 1);  // S uniform across wave
    unsigned h = hist[S * 64 + t];
    unsigned suf2 = h;
    for (int d = 1; d < 64; d <<= 1) {
      unsigned o = __shfl_down(suf2, d);
      if (t + d < 64) suf2 += o;
    }
    unsigned long long m2 = __ballot((suf2 + tail) >= (unsigned)K);
    int Ls = 63 - __clzll(m2);
    if (t == 0) s_cut = S * 64 + Ls;
  }
  __syncthreads();
  const int cut = s_cut;

  // Select candidates with bin >= cut into compact list.
  if (K > 0) {
    for (int i = t; i < n2; i += 256) {
      float sc = cbase[i * 6];
      int bin = (int)(sc * (float)NBINS);
      if (bin > NBINS - 1) bin = NBINS - 1;
      if (bin >= cut) {
        int p = atomicAdd(&s_m, 1);
        if (p < SELCAP) {
          s_ssc[p] = sc;
          s_sfl[p] = ((const int*)cbase)[i * 6 + 5];
          s_sci[p] = i;
        }
      }
    }
  }
  __syncthreads();
  const int m = s_m;

  if (m <= SELCAP) {
    // Exact rank among selected == global rank. O(m^2), m ~ 100-200.
    for (int i = t; i < m; i += 256) {
      float si = s_ssc[i];
      int   fi = s_sfl[i];
      int rank = 0;
#pragma unroll 4
      for (int j = 0; j < m; ++j) {
        float sj = s_ssc[j];
        rank += (int)((sj > si) | ((sj == si) & (s_sfl[j] < fi)));
      }
      if (rank < DETS) {
        int ci = s_sci[i];
        float* dst = dbase + (size_t)rank * 5;
        dst[0] = cbase[ci * 6 + 1];
        dst[1] = cbase[ci * 6 + 2];
        dst[2] = cbase[ci * 6 + 3];
        dst[3] = cbase[ci * 6 + 4];
        dst[4] = si;
        labels_out[img * DETS + rank] = (float)(fi / NN + 1);
      }
    }
  } else {
    // Fallback (mass-tie pathology, never hit on real data): exact O(n^2) rank
    // via broadcast global reads (all lanes read the same j -> L1 broadcast).
    for (int i = t; i < n2; i += 256) {
      float si = cbase[i * 6];
      int   fi = ((const int*)cbase)[i * 6 + 5];
      int rank = 0;
      for (int j = 0; j < n2; ++j) {
        float sj = cbase[j * 6];
        rank += (int)((sj > si) | ((sj == si) & (((const int*)cbase)[j * 6 + 5] < fi)));
      }
      if (rank < DETS) {
        float* dst = dbase + (size_t)rank * 5;
        dst[0] = cbase[i * 6 + 1];
        dst[1] = cbase[i * 6 + 2];
        dst[2] = cbase[i * 6 + 3];
        dst[3] = cbase[i * 6 + 4];
        dst[4] = si;
        labels_out[img * DETS + rank] = (float)(fi / NN + 1);
      }
    }
  }
}

extern "C" void kernel_launch(void* const* d_in, const int* in_sizes, int n_in,
                              void* d_out, int out_size, void* d_ws, size_t ws_size,
                              hipStream_t stream) {
  const float* logits = (const float*)d_in[0];   // [8000, 81]
  const float* reg    = (const float*)d_in[1];   // [8000, 324]
  const float* props  = (const float*)d_in[2];   // [8000, 4]
  // d_in[3] = features, unused (OUTPUT_FEATURE=False)

  float* out = (float*)d_out;                    // dets [8,100,5] then labels [8,100]
  char* ws = (char*)d_ws;
  unsigned* counters = (unsigned*)(ws);                  // u32[16]
  float*    probT    = (float*)(ws + 64);                // [80][8000]
  float*    cand     = (float*)(ws + 64 + 2560000);      // [8][CAP][6]

  softmax_probs<<<(BB * NN + 63) / 64, 64, 0, stream>>>(logits, probT, counters);
  per_class_nms_topk<<<BB * NC, 256, 0, stream>>>(probT, reg, props, counters,
                                                  cand, out, out + BB * DETS * 5);
}

// Round 2
// 118.534 us; speedup vs baseline: 1.3063x; 1.3063x over previous
//
#include <hip/hip_runtime.h>
#include <math.h>

#define BB 8
#define NN 1000
#define CC 81
#define NC 80                     // foreground classes
#define IMG_W_M1 1332.0f
#define IMG_H_M1 799.0f
#define SCORE_THRESH 0.05f
#define NMS_THRESH 0.5f
#define DETS 100
#define CAP 8192                  // per-image candidate capacity after NMS
#define DW_CLIP 4.135166556742356f  // log(1000/16) rounded to f32
#define NBINS 4096
#define SELCAP 1024

// ws layout (bytes):
//   [0, 64)                       u32[16]: counters[0..7] = survivor counts
//   [64, 64 + 80*8000*4)          probT: [80][8000] foreground probs, class-major
//   [2560064, 2560064+8*CAP*6*4)  candidates: per image, CAP x {score, x1,y1,x2,y2, flatidx(int)}
//
// Structure note: 3 separate launches on purpose. Single-kernel fusion requires
// device-scope __threadfence() (buffer_wbl2/buffer_inv on gfx950, L2 writeback
// per block) which measured +26us vs kernel-boundary visibility (round 1).

// Kernel 1: per-row softmax, written TRANSPOSED so kernel 2 reads coalesced.
// Math is bit-identical to the reference path: serial fmax over c=0..80,
// serial sum of expf in the same order, IEEE divide.
__global__ __launch_bounds__(64) void softmax_probs(
    const float* __restrict__ logits, float* __restrict__ probT,
    unsigned* __restrict__ counters) {
#pragma clang fp contract(off)
  if (blockIdx.x == 0 && threadIdx.x < 16) counters[threadIdx.x] = 0u;
  int r = blockIdx.x * 64 + threadIdx.x;
  if (r >= BB * NN) return;
  const float* l = logits + (size_t)r * CC;
  float m = l[0];
#pragma unroll
  for (int c = 1; c < CC; ++c) m = fmaxf(m, l[c]);
  float e[CC];
  float s = 0.0f;
#pragma unroll
  for (int c = 0; c < CC; ++c) { e[c] = expf(l[c] - m); s += e[c]; }
  // transposed store: for fixed c, lanes write 64 consecutive floats.
#pragma unroll
  for (int c = 1; c < CC; ++c)
    probT[(size_t)(c - 1) * (BB * NN) + r] = e[c] / s;
}

// Kernel 2: per-(image,class) candidate filter + sort + decode + greedy NMS.
__global__ __launch_bounds__(256) void per_class_nms(
    const float* __restrict__ probT, const float* __restrict__ reg,
    const float* __restrict__ props, unsigned* __restrict__ counters,
    float* __restrict__ cand) {
#pragma clang fp contract(off)
  __shared__ float s_score[NN];
  __shared__ int   s_idx[NN];
  __shared__ float s_sscore[NN];
  __shared__ int   s_sidx[NN];
  __shared__ float s_box[NN * 4];
  __shared__ unsigned char s_keep[NN];
  __shared__ int s_cnt;
  __shared__ unsigned s_base;

  const int img = blockIdx.x / NC;
  const int cls = blockIdx.x % NC + 1;   // foreground class id 1..80
  const int t = threadIdx.x;

  if (t == 0) s_cnt = 0;
  __syncthreads();

  // Phase 1: collect candidates with prob > thresh — coalesced column read,
  // no expf (precomputed in kernel 1, bitwise-identical values).
  const float* pcol = probT + (size_t)(cls - 1) * (BB * NN) + img * NN;
  for (int r = t; r < NN; r += 256) {
    float p = pcol[r];
    if (p > SCORE_THRESH) {
      int pos = atomicAdd(&s_cnt, 1);
      s_score[pos] = p;
      s_idx[pos] = r;
    }
  }
  __syncthreads();
  const int n = s_cnt;

  // Phase 2: rank sort by (score desc, original row asc) == stable argsort(-scores)
  for (int i = t; i < n; i += 256) {
    float si = s_score[i];
    int   ii = s_idx[i];
    int rank = 0;
#pragma unroll 8
    for (int j = 0; j < n; ++j) {
      float sj = s_score[j];
      rank += (int)((sj > si) | ((sj == si) & (s_idx[j] < ii)));
    }
    s_sscore[rank] = si;
    s_sidx[rank] = ii;
  }
  __syncthreads();

  // Phase 3: decode + clip boxes for sorted candidates (BoxCoder.decode, TO_REMOVE=1)
  for (int i = t; i < n; i += 256) {
    int r = s_sidx[i];
    int row = img * NN + r;
    float x1 = props[row * 4 + 0], y1 = props[row * 4 + 1];
    float x2 = props[row * 4 + 2], y2 = props[row * 4 + 3];
    float w = x2 - x1 + 1.0f, h = y2 - y1 + 1.0f;
    float cx = x1 + 0.5f * w,  cy = y1 + 0.5f * h;
    const float* rg = reg + (size_t)row * (CC * 4) + cls * 4;
    float dx = rg[0] / 10.0f, dy = rg[1] / 10.0f;
    float dw = fminf(rg[2] / 5.0f, DW_CLIP);
    float dh = fminf(rg[3] / 5.0f, DW_CLIP);
    float pcx = dx * w + cx, pcy = dy * h + cy;
    float pw = expf(dw) * w, ph = expf(dh) * h;
    float bx1 = pcx - 0.5f * pw;
    float by1 = pcy - 0.5f * ph;
    float bx2 = pcx + 0.5f * pw - 1.0f;
    float by2 = pcy + 0.5f * ph - 1.0f;
    bx1 = fminf(fmaxf(bx1, 0.0f), IMG_W_M1);
    bx2 = fminf(fmaxf(bx2, 0.0f), IMG_W_M1);
    by1 = fminf(fmaxf(by1, 0.0f), IMG_H_M1);
    by2 = fminf(fmaxf(by2, 0.0f), IMG_H_M1);
    s_box[i * 4 + 0] = bx1;
    s_box[i * 4 + 1] = by1;
    s_box[i * 4 + 2] = bx2;
    s_box[i * 4 + 3] = by2;
    s_keep[i] = 1;
  }
  __syncthreads();

  // Phase 4: greedy NMS, chunk-synchronous. Replaces the n-iteration
  // {work, __syncthreads} loop (n barrier latencies) with 2 barriers per
  // 64-candidate chunk. Semantics identical to sequential greedy:
  //  - resolve: wave 0 serializes over its 64 lanes; suppressor keep-state is
  //    read LIVE via __shfl, and earlier chunks' suppressions already landed
  //    in s_keep via prior sweeps.
  //  - sweep: all 256 threads clear later candidates vs this chunk's keepers.
  const int nch = (n + 63) >> 6;
  for (int c0 = 0; c0 < nch; ++c0) {
    const int i0 = c0 << 6;
    if (t < 64) {
      const int i = i0 + t;
      bool kp = false;
      float bx1 = 0.f, by1 = 0.f, bx2 = 0.f, by2 = 0.f, areaB = 0.f;
      if (i < n) {
        kp = (s_keep[i] != 0);
        bx1 = s_box[i * 4 + 0]; by1 = s_box[i * 4 + 1];
        bx2 = s_box[i * 4 + 2]; by2 = s_box[i * 4 + 3];
        areaB = (bx2 - bx1) * (by2 - by1);
      }
      for (int l = 0; l < 64; ++l) {
        int   kl    = __shfl((int)kp, l);          // live keep of lane l
        float ax1   = __shfl(bx1, l), ay1 = __shfl(by1, l);
        float ax2   = __shfl(bx2, l), ay2 = __shfl(by2, l);
        float areaA = __shfl(areaB, l);
        if (kl && t > l) {
          float wx = fmaxf(fminf(ax2, bx2) - fmaxf(ax1, bx1), 0.0f);
          float wy = fmaxf(fminf(ay2, by2) - fmaxf(ay1, by1), 0.0f);
          float inter = wx * wy;
          float iou = inter / ((areaA + areaB) - inter + 1e-9f);
          if (iou > NMS_THRESH) kp = false;
        }
      }
      if (i < n) s_keep[i] = kp ? 1 : 0;
    }
    __syncthreads();
    const int jbeg = i0 + 64;
    if (jbeg < n) {
      const int kmax = (n - i0 < 64) ? (n - i0) : 64;
      for (int j = jbeg + t; j < n; j += 256) {
        if (!s_keep[j]) continue;
        float bx1 = s_box[j * 4 + 0], by1 = s_box[j * 4 + 1];
        float bx2 = s_box[j * 4 + 2], by2 = s_box[j * 4 + 3];
        float areaB = (bx2 - bx1) * (by2 - by1);
        unsigned char f = 1;
        for (int k = 0; k < kmax; ++k) {
          if (!s_keep[i0 + k]) continue;          // uniform LDS broadcast
          float ax1 = s_box[(i0 + k) * 4 + 0], ay1 = s_box[(i0 + k) * 4 + 1];
          float ax2 = s_box[(i0 + k) * 4 + 2], ay2 = s_box[(i0 + k) * 4 + 3];
          float areaA = (ax2 - ax1) * (ay2 - ay1);
          float wx = fmaxf(fminf(ax2, bx2) - fmaxf(ax1, bx1), 0.0f);
          float wy = fmaxf(fminf(ay2, by2) - fmaxf(ay1, by1), 0.0f);
          float inter = wx * wy;
          float iou = inter / ((areaA + areaB) - inter + 1e-9f);
          if (iou > NMS_THRESH) { f = 0; break; }
        }
        if (!f) s_keep[j] = 0;
      }
    }
    __syncthreads();
  }

  // Phase 5: emit survivors — one global atomic per block, coalesced writes.
  if (t == 0) {
    int tot = 0;
    for (int j = 0; j < n; ++j) tot += s_keep[j];
    s_base = (tot > 0) ? atomicAdd(&counters[img], (unsigned)tot) : 0u;
  }
  __syncthreads();
  for (int i = t; i < n; i += 256) {
    if (s_keep[i]) {
      int pos = 0;
#pragma unroll 4
      for (int j = 0; j < i; ++j) pos += (int)s_keep[j];
      unsigned gpos = s_base + (unsigned)pos;
      if (gpos < CAP) {
        float* c = cand + ((size_t)img * CAP + gpos) * 6;
        c[0] = s_sscore[i];
        c[1] = s_box[i * 4 + 0];
        c[2] = s_box[i * 4 + 1];
        c[3] = s_box[i * 4 + 2];
        c[4] = s_box[i * 4 + 3];
        ((int*)c)[5] = (cls - 1) * NN + s_sidx[i];   // flat idx for tie-break + label
      }
    }
  }
}

#define TK_THREADS 1024

__global__ __launch_bounds__(TK_THREADS) void topk_out(
    const unsigned* __restrict__ counters, const float* __restrict__ cand,
    float* __restrict__ dets_out, float* __restrict__ labels_out) {
#pragma clang fp contract(off)
  __shared__ float s_sc[CAP];
  __shared__ int   s_fl[CAP];
  __shared__ unsigned hist[NBINS];
  __shared__ float s_ssc[SELCAP];
  __shared__ int   s_sfl[SELCAP];
  __shared__ int   s_sci[SELCAP];
  __shared__ int s_m, s_cut;

  const int img = blockIdx.x;
  const int t = threadIdx.x;
  int n = (int)counters[img];
  if (n > CAP) n = CAP;
  const int K = (n < DETS) ? n : DETS;
  const float* cbase = cand + (size_t)img * CAP * 6;

  if (t == 0) { s_m = 0; s_cut = 0; }
  for (int b = t; b < NBINS; b += TK_THREADS) hist[b] = 0u;

  for (int i = t; i < n; i += TK_THREADS) {
    s_sc[i] = cbase[i * 6];
    s_fl[i] = ((const int*)cbase)[i * 6 + 5];
  }
  // Defaults for slots beyond candidate count (ranks 0..K-1 all get written
  // exactly once below, since ranks are unique).
  for (int k = t; k < DETS; k += TK_THREADS) {
    if (k >= K) {
      float* d = dets_out + (size_t)(img * DETS + k) * 5;
      d[0] = 0.0f; d[1] = 0.0f; d[2] = 0.0f; d[3] = 0.0f; d[4] = 0.0f;
      labels_out[img * DETS + k] = -1.0f;
    }
  }
  __syncthreads();

  // Histogram of scores. bin = floor(score*4096) is monotone non-decreasing in
  // score, so {bin >= T} is upward-closed: it contains the exact global top-K,
  // and within-set ranks equal global ranks (excluded => strictly smaller score).
  for (int i = t; i < n; i += TK_THREADS) {
    float sc = s_sc[i];
    int bin = (int)(sc * (float)NBINS);
    if (bin > NBINS - 1) bin = NBINS - 1;
    atomicAdd(&hist[bin], 1u);
  }
  __syncthreads();

  // Wave 0: find largest cutoff bin T with count(bin >= T) >= K.
  if (t < 64 && K > 0) {
    unsigned s = 0;
#pragma unroll
    for (int b = 0; b < 64; ++b) s += hist[t * 64 + b];
    unsigned suf = s;                       // suffix-inclusive scan over 64 superbins
    for (int d = 1; d < 64; d <<= 1) {
      unsigned o = __shfl_down(suf, d);
      if (t + d < 64) suf += o;
    }
    unsigned long long m1 = __ballot(suf >= (unsigned)K);
    int S = 63 - __clzll(m1);               // largest superbin with suffix >= K
    unsigned tail = 0;
    if (S < 63) tail = __shfl(suf, S + 1);  // S uniform across wave
    unsigned h = hist[S * 64 + t];
    unsigned suf2 = h;
    for (int d = 1; d < 64; d <<= 1) {
      unsigned o = __shfl_down(suf2, d);
      if (t + d < 64) suf2 += o;
    }
    unsigned long long m2 = __ballot((suf2 + tail) >= (unsigned)K);
    int Ls = 63 - __clzll(m2);
    if (t == 0) s_cut = S * 64 + Ls;
  }
  __syncthreads();
  const int cut = s_cut;

  // Select candidates with bin >= cut into compact list.
  if (K > 0) {
    for (int i = t; i < n; i += TK_THREADS) {
      float sc = s_sc[i];
      int bin = (int)(sc * (float)NBINS);
      if (bin > NBINS - 1) bin = NBINS - 1;
      if (bin >= cut) {
        int p = atomicAdd(&s_m, 1);
        if (p < SELCAP) { s_ssc[p] = sc; s_sfl[p] = s_fl[i]; s_sci[p] = i; }
      }
    }
  }
  __syncthreads();
  const int m = s_m;

  if (m <= SELCAP) {
    // Exact rank among selected == global rank. O(m^2), m ~ 100-150.
    for (int i = t; i < m; i += TK_THREADS) {
      float si = s_ssc[i];
      int   fi = s_sfl[i];
      int rank = 0;
#pragma unroll 4
      for (int j = 0; j < m; ++j) {
        float sj = s_ssc[j];
        rank += (int)((sj > si) | ((sj == si) & (s_sfl[j] < fi)));
      }
      if (rank < DETS) {
        int ci = s_sci[i];
        float* d = dets_out + (size_t)(img * DETS + rank) * 5;
        d[0] = cbase[ci * 6 + 1];
        d[1] = cbase[ci * 6 + 2];
        d[2] = cbase[ci * 6 + 3];
        d[3] = cbase[ci * 6 + 4];
        d[4] = si;
        labels_out[img * DETS + rank] = (float)(fi / NN + 1);
      }
    }
  } else {
    // Fallback (mass-tie pathology): full O(n^2) rank, provably correct.
    for (int i = t; i < n; i += TK_THREADS) {
      float si = s_sc[i];
      int   fi = s_fl[i];
      int rank = 0;
#pragma unroll 8
      for (int j = 0; j < n; ++j) {
        float sj = s_sc[j];
        rank += (int)((sj > si) | ((sj == si) & (s_fl[j] < fi)));
      }
      if (rank < DETS) {
        float* d = dets_out + (size_t)(img * DETS + rank) * 5;
        d[0] = cbase[i * 6 + 1];
        d[1] = cbase[i * 6 + 2];
        d[2] = cbase[i * 6 + 3];
        d[3] = cbase[i * 6 + 4];
        d[4] = si;
        labels_out[img * DETS + rank] = (float)(fi / NN + 1);
      }
    }
  }
}

extern "C" void kernel_launch(void* const* d_in, const int* in_sizes, int n_in,
                              void* d_out, int out_size, void* d_ws, size_t ws_size,
                              hipStream_t stream) {
  const float* logits = (const float*)d_in[0];   // [8000, 81]
  const float* reg    = (const float*)d_in[1];   // [8000, 324]
  const float* props  = (const float*)d_in[2];   // [8000, 4]
  // d_in[3] = features, unused (OUTPUT_FEATURE=False)

  float* out = (float*)d_out;                    // dets [8,100,5] then labels [8,100]
  char* ws = (char*)d_ws;
  unsigned* counters = (unsigned*)(ws);                  // u32[16]
  float*    probT    = (float*)(ws + 64);                // [80][8000]
  float*    cand     = (float*)(ws + 64 + 2560000);      // [8][CAP][6]

  softmax_probs<<<(BB * NN + 63) / 64, 64, 0, stream>>>(logits, probT, counters);
  per_class_nms<<<BB * NC, 256, 0, stream>>>(probT, reg, props, counters, cand);
  topk_out<<<BB, TK_THREADS, 0, stream>>>(counters, cand, out, out + BB * DETS * 5);
}